// Round 2
// baseline (298.085 us; speedup 1.0000x reference)
//
#include <hip/hip_runtime.h>

typedef __attribute__((ext_vector_type(8))) short bf16x8;
typedef __attribute__((ext_vector_type(8))) _Float16 f16x8;
typedef __attribute__((ext_vector_type(2))) _Float16 f16x2;
typedef __attribute__((ext_vector_type(4))) float f32x4;

__device__ __forceinline__ unsigned short f2bf(float f) {
  union { float f; unsigned int i; } v;
  v.f = f;
  unsigned int r = v.i + 0x7FFFu + ((v.i >> 16) & 1u);  // RNE
  return (unsigned short)(r >> 16);
}

__device__ __forceinline__ f16x2 cvt_pk(float a, float b) {
  return __builtin_bit_cast(f16x2, __builtin_amdgcn_cvt_pkrtz(a, b));
}

// async global->LDS, 16B/lane. LDS dst = wave-uniform base + lane*16.
// Global src MUST be base + lane*16 (contiguous 1KB) for full coalescing —
// all layouts below are fragment-major to guarantee this.
__device__ __forceinline__ void gl_lds16(const unsigned short* g, unsigned short* l) {
  __builtin_amdgcn_global_load_lds(
      (const __attribute__((address_space(1))) unsigned int*)g,
      (__attribute__((address_space(3))) unsigned int*)l, 16, 0, 0);
}

// e^x on [-1,1], Chebyshev-truncated degree 5 (abs err ~5e-5), packed f16.
__device__ __forceinline__ f16x2 exp_poly(f16x2 x) {
  const f16x2 a5 = {(_Float16)0.00868682f, (_Float16)0.00868682f};
  const f16x2 a4 = {(_Float16)0.04379392f, (_Float16)0.04379392f};
  const f16x2 a3 = {(_Float16)0.16648887f, (_Float16)0.16648887f};
  const f16x2 a2 = {(_Float16)0.49919676f, (_Float16)0.49919676f};
  const f16x2 a1 = {(_Float16)1.00002229f, (_Float16)1.00002229f};
  const f16x2 a0 = {(_Float16)1.00004478f, (_Float16)1.00004478f};
#if __has_builtin(__builtin_elementwise_fma)
  f16x2 r = a5;
  r = __builtin_elementwise_fma(r, x, a4);
  r = __builtin_elementwise_fma(r, x, a3);
  r = __builtin_elementwise_fma(r, x, a2);
  r = __builtin_elementwise_fma(r, x, a1);
  r = __builtin_elementwise_fma(r, x, a0);
#else
  f16x2 r = a5;
  r = r * x + a4;
  r = r * x + a3;
  r = r * x + a2;
  r = r * x + a1;
  r = r * x + a0;
#endif
  return r;
}

// ---------------- fp32 -> bf16 convert to FRAGMENT-MAJOR layout ----------------
// Layout: [rtile(=row>>7)][kb(=c>>6)][slot(=((row>>4)&7)*2+((c>>5)&1))]
//         [lane(=((c>>3)&3)*16+(row&15))][e(=c&7)]   (shorts)
__global__ __launch_bounds__(256) void cvt_all(
    const float* __restrict__ x, const float* __restrict__ wq,
    const float* __restrict__ wkv, const float* __restrict__ wo,
    unsigned short* __restrict__ xf, unsigned short* __restrict__ wqf,
    unsigned short* __restrict__ wkvf, unsigned short* __restrict__ wof) {
  int b = blockIdx.x;
  const float* in;
  unsigned short* out;
  int i;
  if (b < 8192) { in = x; out = xf; i = b * 256 + threadIdx.x; }
  else if (b < 8448) { in = wq; out = wqf; i = (b - 8192) * 256 + threadIdx.x; }
  else if (b < 8704) { in = wkv; out = wkvf; i = (b - 8448) * 256 + threadIdx.x; }
  else { in = wo; out = wof; i = (b - 8704) * 256 + threadIdx.x; }
  float4 v = ((const float4*)in)[i];
  int f = i << 2;
  int row = f >> 9, c = f & 511;
  long off = ((((long)(row >> 7) * 8 + (c >> 6)) * 16 + ((row >> 4) & 7) * 2 +
               ((c >> 5) & 1)) * 64 + ((c >> 3) & 3) * 16 + (row & 15)) * 8 + (c & 7);
  ushort4 o;
  o.x = f2bf(v.x);
  o.y = f2bf(v.y);
  o.z = f2bf(v.z);
  o.w = f2bf(v.w);
  *(ushort4*)(out + off) = o;
}

// ---------------- fused Q + KV projection GEMM (fragment-major in) ----------------
// grid (128, 8): y<4 -> Q half (Qn bf16 normalized, row-major),
// y>=4 -> KV half (Kf bf16 normalized fragment-major + Vf f16 V^T fragment-major).
// Kf/Vf layout: [(g*32+kt)*8 + slot][lane][8] shorts, 1KB per slot.
__global__ __launch_bounds__(256) void gemm_qkv(
    const unsigned short* __restrict__ xf, const unsigned short* __restrict__ Wqf,
    const unsigned short* __restrict__ Wkvf, const float* __restrict__ bq,
    const float* __restrict__ bkv, unsigned short* __restrict__ Qn,
    unsigned short* __restrict__ Kf, unsigned short* __restrict__ Vf) {
  __shared__ __attribute__((aligned(16))) unsigned short lA[16 * 512];
  __shared__ __attribute__((aligned(16))) unsigned short lB[16 * 512];
  const int isKV = (int)(blockIdx.y >> 2);
  const unsigned short* Btf = isKV ? Wkvf : Wqf;
  const float* bias = isKV ? bkv : bq;
  const int tid = threadIdx.x;
  const int lane = tid & 63;
  const int quad = lane >> 4, m16 = lane & 15;
  const int w = tid >> 6;
  const int wm = w >> 1, wn = w & 1;
  const long mb = (long)blockIdx.x * 128;
  const int nt = (int)(blockIdx.y & 3);
  const long nb = (long)nt * 128;
  f32x4 acc[4][4];
#pragma unroll
  for (int i = 0; i < 4; i++)
#pragma unroll
    for (int j = 0; j < 4; j++) acc[i][j] = (f32x4){0.f, 0.f, 0.f, 0.f};

  for (int kb = 0; kb < 8; kb++) {
    __syncthreads();
    {
      const unsigned short* gA =
          xf + (((long)blockIdx.x * 8 + kb) * 16 + 4 * w) * 512 + lane * 8;
      gl_lds16(gA, &lA[(4 * w + 0) * 512]);
      gl_lds16(gA + 512, &lA[(4 * w + 1) * 512]);
      gl_lds16(gA + 1024, &lA[(4 * w + 2) * 512]);
      gl_lds16(gA + 1536, &lA[(4 * w + 3) * 512]);
      const unsigned short* gB =
          Btf + (((long)nt * 8 + kb) * 16 + 4 * w) * 512 + lane * 8;
      gl_lds16(gB, &lB[(4 * w + 0) * 512]);
      gl_lds16(gB + 512, &lB[(4 * w + 1) * 512]);
      gl_lds16(gB + 1024, &lB[(4 * w + 2) * 512]);
      gl_lds16(gB + 1536, &lB[(4 * w + 3) * 512]);
    }
    __syncthreads();
#pragma unroll
    for (int ks = 0; ks < 2; ks++) {
      bf16x8 af[4], bfr[4];
#pragma unroll
      for (int i = 0; i < 4; i++)
        af[i] = *(const bf16x8*)&lA[(((wm * 4 + i) << 1) | ks) * 512 + lane * 8];
#pragma unroll
      for (int j = 0; j < 4; j++)
        bfr[j] = *(const bf16x8*)&lB[(((wn * 4 + j) << 1) | ks) * 512 + lane * 8];
#pragma unroll
      for (int i = 0; i < 4; i++)
#pragma unroll
        for (int j = 0; j < 4; j++)
          acc[i][j] =
              __builtin_amdgcn_mfma_f32_16x16x32_bf16(af[i], bfr[j], acc[i][j], 0, 0, 0);
    }
  }
  const int h = (int)(nb >> 6) + wn;  // head is constant per wave-column
#pragma unroll
  for (int i = 0; i < 4; i++) {
    long row0 = mb + wm * 64 + i * 16 + quad * 4;
    float bb[4], val[4][4], inv[4];
#pragma unroll
    for (int j = 0; j < 4; j++) {
      bb[j] = bias[nb + wn * 64 + j * 16 + m16];
#pragma unroll
      for (int r = 0; r < 4; r++) val[j][r] = acc[i][j][r] + bb[j];
    }
#pragma unroll
    for (int r = 0; r < 4; r++) {
      float s = val[0][r] * val[0][r] + val[1][r] * val[1][r] +
                val[2][r] * val[2][r] + val[3][r] * val[3][r];
      s += __shfl_xor(s, 1);
      s += __shfl_xor(s, 2);
      s += __shfl_xor(s, 4);
      s += __shfl_xor(s, 8);
      inv[r] = 1.0f / fmaxf(sqrtf(s), 1e-12f);
    }
    if (!isKV) {
#pragma unroll
      for (int r = 0; r < 4; r++)
#pragma unroll
        for (int j = 0; j < 4; j++) {
          long col = nb + wn * 64 + j * 16 + m16;
          Qn[(row0 + r) * 512 + col] = f2bf(val[j][r] * inv[r]);
        }
    } else {
      const int bm = (int)(row0 >> 11);
      const int g = bm * 8 + h;
      const int kt = (int)((row0 & 2047) >> 6);
      const long tb = ((long)g * 32 + kt) * 8;
      // Kf: element (s,d): slot = i*2+(d>>5), lane = ((d>>3)&3)*16 + (s&15), e = d&7
      //     here d = j*16+m16 -> (d>>5)=j>>1, (d>>3)&3 = ((j&1)<<1)|(m16>>3)
#pragma unroll
      for (int j = 0; j < 4; j++) {
        long kb0 = (tb + i * 2 + (j >> 1)) * 512 +
                   (((((j & 1) << 1) | (m16 >> 3)) * 16 + quad * 4) * 8) + (m16 & 7);
#pragma unroll
        for (int r = 0; r < 4; r++) Kf[kb0 + r * 8] = f2bf(val[j][r] * inv[r]);
      }
      // Vf (V^T): element (d,k): slot = j*2+(i>>1),
      //   lane = (((i&1)<<1)|(quad>>1))*16 + m16, e = (quad&1)*4 + r (contiguous!)
#pragma unroll
      for (int j = 0; j < 4; j++) {
        long vo = (tb + j * 2 + (i >> 1)) * 512 +
                  ((((((i & 1) << 1) | (quad >> 1)) * 16 + m16)) * 8) + (quad & 1) * 4;
        f16x2 lo = cvt_pk(val[j][0], val[j][1]);
        f16x2 hi = cvt_pk(val[j][2], val[j][3]);
        uint2 pk = make_uint2(__builtin_bit_cast(unsigned int, lo),
                              __builtin_bit_cast(unsigned int, hi));
        *(uint2*)(Vf + vo) = pk;
      }
    }
  }
}

// ---------------- output projection GEMM (fragment-major in, f32 out) ----------------
__global__ __launch_bounds__(256) void gemm_o(
    const unsigned short* __restrict__ Af, const unsigned short* __restrict__ Btf,
    const float* __restrict__ bias, float* __restrict__ Cout) {
  __shared__ __attribute__((aligned(16))) unsigned short lA[16 * 512];
  __shared__ __attribute__((aligned(16))) unsigned short lB[16 * 512];
  const int tid = threadIdx.x;
  const int lane = tid & 63;
  const int quad = lane >> 4, m16 = lane & 15;
  const int w = tid >> 6;
  const int wm = w >> 1, wn = w & 1;
  const long mb = (long)blockIdx.x * 128;
  const int nt = (int)blockIdx.y;
  const long nb = (long)nt * 128;
  f32x4 acc[4][4];
#pragma unroll
  for (int i = 0; i < 4; i++)
#pragma unroll
    for (int j = 0; j < 4; j++) acc[i][j] = (f32x4){0.f, 0.f, 0.f, 0.f};

  for (int kb = 0; kb < 8; kb++) {
    __syncthreads();
    {
      const unsigned short* gA =
          Af + (((long)blockIdx.x * 8 + kb) * 16 + 4 * w) * 512 + lane * 8;
      gl_lds16(gA, &lA[(4 * w + 0) * 512]);
      gl_lds16(gA + 512, &lA[(4 * w + 1) * 512]);
      gl_lds16(gA + 1024, &lA[(4 * w + 2) * 512]);
      gl_lds16(gA + 1536, &lA[(4 * w + 3) * 512]);
      const unsigned short* gB =
          Btf + (((long)nt * 8 + kb) * 16 + 4 * w) * 512 + lane * 8;
      gl_lds16(gB, &lB[(4 * w + 0) * 512]);
      gl_lds16(gB + 512, &lB[(4 * w + 1) * 512]);
      gl_lds16(gB + 1024, &lB[(4 * w + 2) * 512]);
      gl_lds16(gB + 1536, &lB[(4 * w + 3) * 512]);
    }
    __syncthreads();
#pragma unroll
    for (int ks = 0; ks < 2; ks++) {
      bf16x8 af[4], bfr[4];
#pragma unroll
      for (int i = 0; i < 4; i++)
        af[i] = *(const bf16x8*)&lA[(((wm * 4 + i) << 1) | ks) * 512 + lane * 8];
#pragma unroll
      for (int j = 0; j < 4; j++)
        bfr[j] = *(const bf16x8*)&lB[(((wn * 4 + j) << 1) | ks) * 512 + lane * 8];
#pragma unroll
      for (int i = 0; i < 4; i++)
#pragma unroll
        for (int j = 0; j < 4; j++)
          acc[i][j] =
              __builtin_amdgcn_mfma_f32_16x16x32_bf16(af[i], bfr[j], acc[i][j], 0, 0, 0);
    }
  }
#pragma unroll
  for (int i = 0; i < 4; i++) {
    long row0 = mb + wm * 64 + i * 16 + quad * 4;
#pragma unroll
    for (int j = 0; j < 4; j++) {
      long col = nb + wn * 64 + j * 16 + m16;
      float bb = bias[col];
#pragma unroll
      for (int r = 0; r < 4; r++) Cout[(row0 + r) * 512 + col] = acc[i][j][r] + bb;
    }
  }
}

// ---------------- cosine attention (T14 reg-staged LDS pipeline) ----------------
// grid (64, 16): blockIdx.x = head-group g so all 16 q-tile blocks of a group
// land on the same XCD (dispatch id % 8) -> the group's 512 KB K/V stays
// L2-resident (8 groups x 512 KB = 4 MB = one XCD L2).
// Per kt: ds_write(staged regs) -> __syncthreads (vmcnt(0) free: nothing in
// flight) -> issue global loads for kt+1 into regs (latency hides under the
// full kt compute) -> compute -> lgkmcnt(0) + RAW s_barrier (prefetch stays
// in flight across it — this was the round-0 structural stall).
__global__ __launch_bounds__(256, 4) void attn_cos(
    const unsigned short* __restrict__ Qn, const unsigned short* __restrict__ Kf,
    const unsigned short* __restrict__ Vf, unsigned short* __restrict__ ctxf) {
  __shared__ __attribute__((aligned(16))) unsigned short lK[8 * 512];   // 8 KB
  __shared__ __attribute__((aligned(16))) unsigned short lVt[8 * 512];  // 8 KB
  __shared__ __attribute__((aligned(16))) unsigned short lP[64 * 64];   // 8 KB
  const int g = blockIdx.x;   // 0..63
  const int qt = blockIdx.y;  // 0..15
  const int bm = g >> 3, h = g & 7;
  const int tid = threadIdx.x;
  const int lane = tid & 63;
  const int quad = lane >> 4, m16 = lane & 15;
  const int w = tid >> 6;
  const long rowbase = (long)bm * 2048;
  const int colbase = h * 64;
  const long qrow0 = rowbase + qt * 128 + w * 32;
  const int swz = (m16 & 7) << 3;            // lP XOR swizzle key
  unsigned short* myP = lP + (w * 16) * 64;  // wave-private 2KB (one 16-row tile)

  // Q B-fragments (fixed for all k-tiles; one-time strided load, row-major Qn)
  bf16x8 qf[2][2];
#pragma unroll
  for (int i = 0; i < 2; i++)
#pragma unroll
    for (int ks = 0; ks < 2; ks++)
      qf[i][ks] = *(const bf16x8*)(Qn + (qrow0 + i * 16 + m16) * 512 + colbase +
                                   ks * 32 + quad * 8);

  f32x4 cacc[2][4];
#pragma unroll
  for (int i = 0; i < 2; i++)
#pragma unroll
    for (int j = 0; j < 4; j++) cacc[i][j] = (f32x4){0.f, 0.f, 0.f, 0.f};
  f32x4 cacc_l[2];  // li via PV-ones MFMA: D[q][*] = sum_k P[q][k]
  cacc_l[0] = (f32x4){0.f, 0.f, 0.f, 0.f};
  cacc_l[1] = (f32x4){0.f, 0.f, 0.f, 0.f};
  const f16x8 onesv = {(_Float16)1.0f, (_Float16)1.0f, (_Float16)1.0f, (_Float16)1.0f,
                       (_Float16)1.0f, (_Float16)1.0f, (_Float16)1.0f, (_Float16)1.0f};

  // prologue: stage kt=0 into regs (wave w owns slots 2w, 2w+1 of K and V)
  uint4 stK0, stK1, stV0, stV1;
  {
    const long tb = (long)g * 32 * 8;
    const unsigned short* pk = Kf + (tb + 2 * w) * 512 + lane * 8;
    const unsigned short* pv = Vf + (tb + 2 * w) * 512 + lane * 8;
    stK0 = *(const uint4*)pk;
    stK1 = *(const uint4*)(pk + 512);
    stV0 = *(const uint4*)pv;
    stV1 = *(const uint4*)(pv + 512);
  }

  for (int kt = 0; kt < 32; ++kt) {
    // write staged tile kt to LDS (conflict-free: lane*16B stride-1)
    *(uint4*)&lK[(2 * w + 0) * 512 + lane * 8] = stK0;
    *(uint4*)&lK[(2 * w + 1) * 512 + lane * 8] = stK1;
    *(uint4*)&lVt[(2 * w + 0) * 512 + lane * 8] = stV0;
    *(uint4*)&lVt[(2 * w + 1) * 512 + lane * 8] = stV1;
    __syncthreads();  // implicit vmcnt(0) is FREE here: no vmem in flight

    // prefetch kt+1 into regs; consumed by next iteration's ds_write
    {
      const int ktn = (kt + 1) & 31;
      const long tb = ((long)g * 32 + ktn) * 8;
      const unsigned short* pk = Kf + (tb + 2 * w) * 512 + lane * 8;
      const unsigned short* pv = Vf + (tb + 2 * w) * 512 + lane * 8;
      stK0 = *(const uint4*)pk;
      stK1 = *(const uint4*)(pk + 512);
      stV0 = *(const uint4*)pv;
      stV1 = *(const uint4*)(pv + 512);
    }
    __builtin_amdgcn_sched_barrier(0);  // pin load issue before compute

    // compute: one 16-row q-tile at a time (keeps peak VGPR under 128)
#pragma unroll
    for (int i = 0; i < 2; i++) {
      f32x4 sacc[4];
#pragma unroll
      for (int j = 0; j < 4; j++) sacc[j] = (f32x4){0.f, 0.f, 0.f, 0.f};
#pragma unroll
      for (int ks = 0; ks < 2; ++ks) {
        bf16x8 kfr[4];
#pragma unroll
        for (int j = 0; j < 4; j++)
          kfr[j] = *(const bf16x8*)&lK[((j << 1) | ks) * 512 + lane * 8];
#pragma unroll
        for (int j = 0; j < 4; j++)
          sacc[j] = __builtin_amdgcn_mfma_f32_16x16x32_bf16(kfr[j], qf[i][ks],
                                                            sacc[j], 0, 0, 0);
      }
      // packed-f16 exp + swizzled P write (wave-private rows, no barrier)
#pragma unroll
      for (int j = 0; j < 4; j++) {
        f16x2 x01 = cvt_pk(sacc[j][0], sacc[j][1]);
        f16x2 x23 = cvt_pk(sacc[j][2], sacc[j][3]);
        f16x2 e01 = exp_poly(x01);
        f16x2 e23 = exp_poly(x23);
        uint2 pk2 = make_uint2(__builtin_bit_cast(unsigned int, e01),
                               __builtin_bit_cast(unsigned int, e23));
        *(uint2*)&myP[m16 * 64 + ((j * 16 + quad * 4) ^ swz)] = pk2;
      }
      // PV (f16) + li row-sum via ones-MFMA (moves li off the VALU pipe)
#pragma unroll
      for (int ks = 0; ks < 2; ++ks) {
        f16x8 pfr = *(const f16x8*)&myP[m16 * 64 + ((ks * 32 + quad * 8) ^ swz)];
        f16x8 vfr[4];
#pragma unroll
        for (int j = 0; j < 4; j++)
          vfr[j] = *(const f16x8*)&lVt[((j << 1) | ks) * 512 + lane * 8];
#pragma unroll
        for (int j = 0; j < 4; j++)
          cacc[i][j] = __builtin_amdgcn_mfma_f32_16x16x32_f16(pfr, vfr[j],
                                                              cacc[i][j], 0, 0, 0);
        cacc_l[i] =
            __builtin_amdgcn_mfma_f32_16x16x32_f16(pfr, onesv, cacc_l[i], 0, 0, 0);
      }
    }
    // raw barrier: this wave's LDS ops are done (lgkmcnt 0), but the global
    // prefetch stays in flight — no vmcnt drain (the round-0 stall).
    asm volatile("s_waitcnt lgkmcnt(0)" ::: "memory");
    __builtin_amdgcn_s_barrier();
    __builtin_amdgcn_sched_barrier(0);
  }

  // li is replicated across columns of cacc_l; rows match cacc rows -> no shuffles
  float linv[2][4];
#pragma unroll
  for (int i = 0; i < 2; i++)
#pragma unroll
    for (int r = 0; r < 4; r++) linv[i][r] = 1.0f / cacc_l[i][r];
  // epilogue: write ctx FRAGMENT-MAJOR for gemm_o:
  // rtile = bm*16+qt, kb = h, slot = (w*2+i)*2 + (j>>1),
  // lane = (((j&1)<<1)|(m16>>3))*16 + quad*4 + r, e = m16&7
  const long cb0 = (((long)(bm * 16 + qt) * 8 + h) * 16);
#pragma unroll
  for (int i = 0; i < 2; i++)
#pragma unroll
    for (int j = 0; j < 4; j++) {
      long off = (cb0 + (w * 2 + i) * 2 + (j >> 1)) * 512 +
                 (((((j & 1) << 1) | (m16 >> 3)) * 16 + quad * 4) * 8) + (m16 & 7);
#pragma unroll
      for (int r = 0; r < 4; r++)
        ctxf[off + r * 8] = f2bf(cacc[i][j][r] * linv[i][r]);
    }
}

extern "C" void kernel_launch(void* const* d_in, const int* in_sizes, int n_in,
                              void* d_out, int out_size, void* d_ws, size_t ws_size,
                              hipStream_t stream) {
  (void)in_sizes; (void)n_in; (void)out_size; (void)ws_size;
  const float* x = (const float*)d_in[0];
  const float* Wq = (const float*)d_in[1];
  const float* bq = (const float*)d_in[2];
  const float* Wkv = (const float*)d_in[3];
  const float* bkv = (const float*)d_in[4];
  const float* Wo = (const float*)d_in[5];
  const float* bo = (const float*)d_in[6];

  char* ws = (char*)d_ws;
  unsigned short* xf     = (unsigned short*)(ws);             // 16 MiB (reused as ctxf)
  unsigned short* Wqf    = (unsigned short*)(ws + 16777216);  // 512 KiB
  unsigned short* Wkvf   = (unsigned short*)(ws + 17301504);  // 512 KiB
  unsigned short* Wof    = (unsigned short*)(ws + 17825792);  // 512 KiB
  unsigned short* Qn_bf  = (unsigned short*)(ws + 18350080);  // 16 MiB
  unsigned short* Kf     = (unsigned short*)(ws + 35127296);  // 16 MiB
  unsigned short* Vf     = (unsigned short*)(ws + 51904512);  // 16 MiB
  unsigned short* ctxf   = xf;  // x dead after gemm_qkv

  cvt_all<<<8960, 256, 0, stream>>>(x, Wq, Wkv, Wo, xf, Wqf, Wkvf, Wof);

  gemm_qkv<<<dim3(128, 8), 256, 0, stream>>>(xf, Wqf, Wkvf, bq, bkv, Qn_bf, Kf, Vf);

  attn_cos<<<dim3(64, 16), 256, 0, stream>>>(Qn_bf, Kf, Vf, ctxf);

  gemm_o<<<dim3(128, 4), 256, 0, stream>>>(ctxf, Wof, bo, (float*)d_out);
}

// Round 3
// 228.148 us; speedup vs baseline: 1.3065x; 1.3065x over previous
//
#include <hip/hip_runtime.h>

typedef __attribute__((ext_vector_type(8))) short bf16x8;
typedef __attribute__((ext_vector_type(8))) _Float16 f16x8;
typedef __attribute__((ext_vector_type(2))) _Float16 f16x2;
typedef __attribute__((ext_vector_type(4))) float f32x4;

__device__ __forceinline__ unsigned short f2bf(float f) {
  union { float f; unsigned int i; } v;
  v.f = f;
  unsigned int r = v.i + 0x7FFFu + ((v.i >> 16) & 1u);  // RNE
  return (unsigned short)(r >> 16);
}

__device__ __forceinline__ f16x2 cvt_pk(float a, float b) {
  return __builtin_bit_cast(f16x2, __builtin_amdgcn_cvt_pkrtz(a, b));
}

// async global->LDS, 16B/lane. LDS dst = wave-uniform base + lane*16.
// Global src MUST be base + lane*16 (contiguous 1KB) for full coalescing —
// all layouts below are fragment-major to guarantee this.
__device__ __forceinline__ void gl_lds16(const unsigned short* g, unsigned short* l) {
  __builtin_amdgcn_global_load_lds(
      (const __attribute__((address_space(1))) unsigned int*)g,
      (__attribute__((address_space(3))) unsigned int*)l, 16, 0, 0);
}

// e^x on [-1,1], Chebyshev-truncated degree 5 (abs err ~5e-5), packed f16.
__device__ __forceinline__ f16x2 exp_poly(f16x2 x) {
  const f16x2 a5 = {(_Float16)0.00868682f, (_Float16)0.00868682f};
  const f16x2 a4 = {(_Float16)0.04379392f, (_Float16)0.04379392f};
  const f16x2 a3 = {(_Float16)0.16648887f, (_Float16)0.16648887f};
  const f16x2 a2 = {(_Float16)0.49919676f, (_Float16)0.49919676f};
  const f16x2 a1 = {(_Float16)1.00002229f, (_Float16)1.00002229f};
  const f16x2 a0 = {(_Float16)1.00004478f, (_Float16)1.00004478f};
#if __has_builtin(__builtin_elementwise_fma)
  f16x2 r = a5;
  r = __builtin_elementwise_fma(r, x, a4);
  r = __builtin_elementwise_fma(r, x, a3);
  r = __builtin_elementwise_fma(r, x, a2);
  r = __builtin_elementwise_fma(r, x, a1);
  r = __builtin_elementwise_fma(r, x, a0);
#else
  f16x2 r = a5;
  r = r * x + a4;
  r = r * x + a3;
  r = r * x + a2;
  r = r * x + a1;
  r = r * x + a0;
#endif
  return r;
}

// ---------------- fp32 -> bf16 convert to FRAGMENT-MAJOR layout ----------------
// Layout: [rtile(=row>>7)][kb(=c>>6)][slot(=((row>>4)&7)*2+((c>>5)&1))]
//         [lane(=((c>>3)&3)*16+(row&15))][e(=c&7)]   (shorts)
__global__ __launch_bounds__(256) void cvt_all(
    const float* __restrict__ x, const float* __restrict__ wq,
    const float* __restrict__ wkv, const float* __restrict__ wo,
    unsigned short* __restrict__ xf, unsigned short* __restrict__ wqf,
    unsigned short* __restrict__ wkvf, unsigned short* __restrict__ wof) {
  int b = blockIdx.x;
  const float* in;
  unsigned short* out;
  int i;
  if (b < 8192) { in = x; out = xf; i = b * 256 + threadIdx.x; }
  else if (b < 8448) { in = wq; out = wqf; i = (b - 8192) * 256 + threadIdx.x; }
  else if (b < 8704) { in = wkv; out = wkvf; i = (b - 8448) * 256 + threadIdx.x; }
  else { in = wo; out = wof; i = (b - 8704) * 256 + threadIdx.x; }
  float4 v = ((const float4*)in)[i];
  int f = i << 2;
  int row = f >> 9, c = f & 511;
  long off = ((((long)(row >> 7) * 8 + (c >> 6)) * 16 + ((row >> 4) & 7) * 2 +
               ((c >> 5) & 1)) * 64 + ((c >> 3) & 3) * 16 + (row & 15)) * 8 + (c & 7);
  ushort4 o;
  o.x = f2bf(v.x);
  o.y = f2bf(v.y);
  o.z = f2bf(v.z);
  o.w = f2bf(v.w);
  *(ushort4*)(out + off) = o;
}

// ---------------- fused Q + KV projection GEMM (fragment-major in) ----------------
// grid (128, 8): y<4 -> Q half (Qn bf16 normalized, row-major),
// y>=4 -> KV half (Kf bf16 normalized fragment-major + Vf f16 V^T fragment-major).
// Kf/Vf layout: [(g*32+kt)*8 + slot][lane][8] shorts, 1KB per slot.
__global__ __launch_bounds__(256) void gemm_qkv(
    const unsigned short* __restrict__ xf, const unsigned short* __restrict__ Wqf,
    const unsigned short* __restrict__ Wkvf, const float* __restrict__ bq,
    const float* __restrict__ bkv, unsigned short* __restrict__ Qn,
    unsigned short* __restrict__ Kf, unsigned short* __restrict__ Vf) {
  __shared__ __attribute__((aligned(16))) unsigned short lA[16 * 512];
  __shared__ __attribute__((aligned(16))) unsigned short lB[16 * 512];
  const int isKV = (int)(blockIdx.y >> 2);
  const unsigned short* Btf = isKV ? Wkvf : Wqf;
  const float* bias = isKV ? bkv : bq;
  const int tid = threadIdx.x;
  const int lane = tid & 63;
  const int quad = lane >> 4, m16 = lane & 15;
  const int w = tid >> 6;
  const int wm = w >> 1, wn = w & 1;
  const long mb = (long)blockIdx.x * 128;
  const int nt = (int)(blockIdx.y & 3);
  const long nb = (long)nt * 128;
  f32x4 acc[4][4];
#pragma unroll
  for (int i = 0; i < 4; i++)
#pragma unroll
    for (int j = 0; j < 4; j++) acc[i][j] = (f32x4){0.f, 0.f, 0.f, 0.f};

  for (int kb = 0; kb < 8; kb++) {
    __syncthreads();
    {
      const unsigned short* gA =
          xf + (((long)blockIdx.x * 8 + kb) * 16 + 4 * w) * 512 + lane * 8;
      gl_lds16(gA, &lA[(4 * w + 0) * 512]);
      gl_lds16(gA + 512, &lA[(4 * w + 1) * 512]);
      gl_lds16(gA + 1024, &lA[(4 * w + 2) * 512]);
      gl_lds16(gA + 1536, &lA[(4 * w + 3) * 512]);
      const unsigned short* gB =
          Btf + (((long)nt * 8 + kb) * 16 + 4 * w) * 512 + lane * 8;
      gl_lds16(gB, &lB[(4 * w + 0) * 512]);
      gl_lds16(gB + 512, &lB[(4 * w + 1) * 512]);
      gl_lds16(gB + 1024, &lB[(4 * w + 2) * 512]);
      gl_lds16(gB + 1536, &lB[(4 * w + 3) * 512]);
    }
    __syncthreads();
#pragma unroll
    for (int ks = 0; ks < 2; ks++) {
      bf16x8 af[4], bfr[4];
#pragma unroll
      for (int i = 0; i < 4; i++)
        af[i] = *(const bf16x8*)&lA[(((wm * 4 + i) << 1) | ks) * 512 + lane * 8];
#pragma unroll
      for (int j = 0; j < 4; j++)
        bfr[j] = *(const bf16x8*)&lB[(((wn * 4 + j) << 1) | ks) * 512 + lane * 8];
#pragma unroll
      for (int i = 0; i < 4; i++)
#pragma unroll
        for (int j = 0; j < 4; j++)
          acc[i][j] =
              __builtin_amdgcn_mfma_f32_16x16x32_bf16(af[i], bfr[j], acc[i][j], 0, 0, 0);
    }
  }
  const int h = (int)(nb >> 6) + wn;  // head is constant per wave-column
#pragma unroll
  for (int i = 0; i < 4; i++) {
    long row0 = mb + wm * 64 + i * 16 + quad * 4;
    float bb[4], val[4][4], inv[4];
#pragma unroll
    for (int j = 0; j < 4; j++) {
      bb[j] = bias[nb + wn * 64 + j * 16 + m16];
#pragma unroll
      for (int r = 0; r < 4; r++) val[j][r] = acc[i][j][r] + bb[j];
    }
#pragma unroll
    for (int r = 0; r < 4; r++) {
      float s = val[0][r] * val[0][r] + val[1][r] * val[1][r] +
                val[2][r] * val[2][r] + val[3][r] * val[3][r];
      s += __shfl_xor(s, 1);
      s += __shfl_xor(s, 2);
      s += __shfl_xor(s, 4);
      s += __shfl_xor(s, 8);
      inv[r] = 1.0f / fmaxf(sqrtf(s), 1e-12f);
    }
    if (!isKV) {
#pragma unroll
      for (int r = 0; r < 4; r++)
#pragma unroll
        for (int j = 0; j < 4; j++) {
          long col = nb + wn * 64 + j * 16 + m16;
          Qn[(row0 + r) * 512 + col] = f2bf(val[j][r] * inv[r]);
        }
    } else {
      const int bm = (int)(row0 >> 11);
      const int g = bm * 8 + h;
      const int kt = (int)((row0 & 2047) >> 6);
      const long tb = ((long)g * 32 + kt) * 8;
      // Kf: element (s,d): slot = i*2+(d>>5), lane = ((d>>3)&3)*16 + (s&15), e = d&7
      //     here d = j*16+m16 -> (d>>5)=j>>1, (d>>3)&3 = ((j&1)<<1)|(m16>>3)
#pragma unroll
      for (int j = 0; j < 4; j++) {
        long kb0 = (tb + i * 2 + (j >> 1)) * 512 +
                   (((((j & 1) << 1) | (m16 >> 3)) * 16 + quad * 4) * 8) + (m16 & 7);
#pragma unroll
        for (int r = 0; r < 4; r++) Kf[kb0 + r * 8] = f2bf(val[j][r] * inv[r]);
      }
      // Vf (V^T): element (d,k): slot = j*2+(i>>1),
      //   lane = (((i&1)<<1)|(quad>>1))*16 + m16, e = (quad&1)*4 + r (contiguous!)
#pragma unroll
      for (int j = 0; j < 4; j++) {
        long vo = (tb + j * 2 + (i >> 1)) * 512 +
                  ((((((i & 1) << 1) | (quad >> 1)) * 16 + m16)) * 8) + (quad & 1) * 4;
        f16x2 lo = cvt_pk(val[j][0], val[j][1]);
        f16x2 hi = cvt_pk(val[j][2], val[j][3]);
        uint2 pk = make_uint2(__builtin_bit_cast(unsigned int, lo),
                              __builtin_bit_cast(unsigned int, hi));
        *(uint2*)(Vf + vo) = pk;
      }
    }
  }
}

// ---------------- output projection GEMM (fragment-major in, f32 out) ----------------
__global__ __launch_bounds__(256) void gemm_o(
    const unsigned short* __restrict__ Af, const unsigned short* __restrict__ Btf,
    const float* __restrict__ bias, float* __restrict__ Cout) {
  __shared__ __attribute__((aligned(16))) unsigned short lA[16 * 512];
  __shared__ __attribute__((aligned(16))) unsigned short lB[16 * 512];
  const int tid = threadIdx.x;
  const int lane = tid & 63;
  const int quad = lane >> 4, m16 = lane & 15;
  const int w = tid >> 6;
  const int wm = w >> 1, wn = w & 1;
  const long mb = (long)blockIdx.x * 128;
  const int nt = (int)blockIdx.y;
  const long nb = (long)nt * 128;
  f32x4 acc[4][4];
#pragma unroll
  for (int i = 0; i < 4; i++)
#pragma unroll
    for (int j = 0; j < 4; j++) acc[i][j] = (f32x4){0.f, 0.f, 0.f, 0.f};

  for (int kb = 0; kb < 8; kb++) {
    __syncthreads();
    {
      const unsigned short* gA =
          Af + (((long)blockIdx.x * 8 + kb) * 16 + 4 * w) * 512 + lane * 8;
      gl_lds16(gA, &lA[(4 * w + 0) * 512]);
      gl_lds16(gA + 512, &lA[(4 * w + 1) * 512]);
      gl_lds16(gA + 1024, &lA[(4 * w + 2) * 512]);
      gl_lds16(gA + 1536, &lA[(4 * w + 3) * 512]);
      const unsigned short* gB =
          Btf + (((long)nt * 8 + kb) * 16 + 4 * w) * 512 + lane * 8;
      gl_lds16(gB, &lB[(4 * w + 0) * 512]);
      gl_lds16(gB + 512, &lB[(4 * w + 1) * 512]);
      gl_lds16(gB + 1024, &lB[(4 * w + 2) * 512]);
      gl_lds16(gB + 1536, &lB[(4 * w + 3) * 512]);
    }
    __syncthreads();
#pragma unroll
    for (int ks = 0; ks < 2; ks++) {
      bf16x8 af[4], bfr[4];
#pragma unroll
      for (int i = 0; i < 4; i++)
        af[i] = *(const bf16x8*)&lA[(((wm * 4 + i) << 1) | ks) * 512 + lane * 8];
#pragma unroll
      for (int j = 0; j < 4; j++)
        bfr[j] = *(const bf16x8*)&lB[(((wn * 4 + j) << 1) | ks) * 512 + lane * 8];
#pragma unroll
      for (int i = 0; i < 4; i++)
#pragma unroll
        for (int j = 0; j < 4; j++)
          acc[i][j] =
              __builtin_amdgcn_mfma_f32_16x16x32_bf16(af[i], bfr[j], acc[i][j], 0, 0, 0);
    }
  }
#pragma unroll
  for (int i = 0; i < 4; i++) {
    long row0 = mb + wm * 64 + i * 16 + quad * 4;
#pragma unroll
    for (int j = 0; j < 4; j++) {
      long col = nb + wn * 64 + j * 16 + m16;
      float bb = bias[col];
#pragma unroll
      for (int r = 0; r < 4; r++) Cout[(row0 + r) * 512 + col] = acc[i][j][r] + bb;
    }
  }
}

// ---------------- cosine attention (8-wave blocks, L2-set-aware mapping) ----------------
// 512 blocks x 8 waves; each block covers 256 q-rows of one group => only 8
// blocks per group re-read its 512 KB K/V (halved L2-side demand vs 16).
// Block-id decode g=(id>>6)*8+(id&7), qt=(id>>3)&7 puts EXACTLY 8 distinct
// groups (4 MB K/V = one L2) per XCD under BOTH plausible XCD-assignment
// models (round-robin id%8 and chunked id/64). All 512 blocks co-resident.
__global__ __launch_bounds__(512, 4) void attn_cos(
    const unsigned short* __restrict__ Qn, const unsigned short* __restrict__ Kf,
    const unsigned short* __restrict__ Vf, unsigned short* __restrict__ ctxf) {
  __shared__ __attribute__((aligned(16))) unsigned short lK[8 * 512];   // 8 KB
  __shared__ __attribute__((aligned(16))) unsigned short lVt[8 * 512];  // 8 KB
  __shared__ __attribute__((aligned(16))) unsigned short lP[256 * 64];  // 32 KB
  const int id = (int)blockIdx.x;
  const int g = ((id >> 6) << 3) | (id & 7);  // 0..63
  const int qt = (id >> 3) & 7;               // 0..7 (256-row tiles)
  const int bm = g >> 3, h = g & 7;
  const int tid = threadIdx.x;
  const int lane = tid & 63;
  const int quad = lane >> 4, m16 = lane & 15;
  const int w = tid >> 6;  // 0..7
  const long qrow0 = (long)bm * 2048 + qt * 256 + w * 32;
  const int colbase = h * 64;
  const int swz = (m16 & 7) << 3;            // lP XOR swizzle key
  unsigned short* myP = lP + (w * 32) * 64;  // wave-private 4KB (32 rows)

  // Q B-fragments (fixed for all k-tiles; one-time strided load, row-major Qn)
  bf16x8 qf[2][2];
#pragma unroll
  for (int i = 0; i < 2; i++)
#pragma unroll
    for (int ks = 0; ks < 2; ks++)
      qf[i][ks] = *(const bf16x8*)(Qn + (qrow0 + i * 16 + m16) * 512 + colbase +
                                   ks * 32 + quad * 8);

  f32x4 cacc[2][4];
#pragma unroll
  for (int i = 0; i < 2; i++)
#pragma unroll
    for (int j = 0; j < 4; j++) cacc[i][j] = (f32x4){0.f, 0.f, 0.f, 0.f};
  f32x4 cacc_l[2];  // li via PV-ones MFMA: every column of D = row-sum of P
  cacc_l[0] = (f32x4){0.f, 0.f, 0.f, 0.f};
  cacc_l[1] = (f32x4){0.f, 0.f, 0.f, 0.f};
  const f16x8 onesv = {(_Float16)1.0f, (_Float16)1.0f, (_Float16)1.0f, (_Float16)1.0f,
                       (_Float16)1.0f, (_Float16)1.0f, (_Float16)1.0f, (_Float16)1.0f};

  for (int kt = 0; kt < 32; ++kt) {
    const long tb = ((long)g * 32 + kt) * 8;
    __syncthreads();
    // cooperative stage: wave w fills slot w of K and of V (1KB each)
    gl_lds16(Kf + (tb + w) * 512 + lane * 8, &lK[w * 512]);
    gl_lds16(Vf + (tb + w) * 512 + lane * 8, &lVt[w * 512]);
    __syncthreads();

#pragma unroll
    for (int i = 0; i < 2; i++) {
      f32x4 sacc[4];
#pragma unroll
      for (int j = 0; j < 4; j++) sacc[j] = (f32x4){0.f, 0.f, 0.f, 0.f};
#pragma unroll
      for (int ks = 0; ks < 2; ++ks) {
        bf16x8 kfr[4];
#pragma unroll
        for (int j = 0; j < 4; j++)
          kfr[j] = *(const bf16x8*)&lK[((j << 1) | ks) * 512 + lane * 8];
#pragma unroll
        for (int j = 0; j < 4; j++)
          sacc[j] = __builtin_amdgcn_mfma_f32_16x16x32_bf16(kfr[j], qf[i][ks],
                                                            sacc[j], 0, 0, 0);
      }
      // packed-f16 exp + swizzled P write (wave-private rows, no barrier)
#pragma unroll
      for (int j = 0; j < 4; j++) {
        f16x2 x01 = cvt_pk(sacc[j][0], sacc[j][1]);
        f16x2 x23 = cvt_pk(sacc[j][2], sacc[j][3]);
        f16x2 e01 = exp_poly(x01);
        f16x2 e23 = exp_poly(x23);
        uint2 pk2 = make_uint2(__builtin_bit_cast(unsigned int, e01),
                               __builtin_bit_cast(unsigned int, e23));
        *(uint2*)&myP[(i * 16 + m16) * 64 + ((j * 16 + quad * 4) ^ swz)] = pk2;
      }
      // PV (f16) + li row-sum via ones-MFMA (off the VALU pipe)
#pragma unroll
      for (int ks = 0; ks < 2; ++ks) {
        f16x8 pfr = *(const f16x8*)&myP[(i * 16 + m16) * 64 +
                                        ((ks * 32 + quad * 8) ^ swz)];
        f16x8 vfr[4];
#pragma unroll
        for (int j = 0; j < 4; j++)
          vfr[j] = *(const f16x8*)&lVt[((j << 1) | ks) * 512 + lane * 8];
#pragma unroll
        for (int j = 0; j < 4; j++)
          cacc[i][j] = __builtin_amdgcn_mfma_f32_16x16x32_f16(pfr, vfr[j],
                                                              cacc[i][j], 0, 0, 0);
        cacc_l[i] =
            __builtin_amdgcn_mfma_f32_16x16x32_f16(pfr, onesv, cacc_l[i], 0, 0, 0);
      }
    }
  }

  // li rows of cacc_l match cacc rows -> no shuffles needed
  float linv[2][4];
#pragma unroll
  for (int i = 0; i < 2; i++)
#pragma unroll
    for (int r = 0; r < 4; r++) linv[i][r] = 1.0f / cacc_l[i][r];
  // epilogue: write ctx FRAGMENT-MAJOR for gemm_o:
  // rtile = bm*16 + qt*2 + (w>>2), kb = h, slot = ((w&3)*2+i)*2 + (j>>1),
  // lane = (((j&1)<<1)|(m16>>3))*16 + quad*4 + r, e = m16&7
  const long cb0 = (((long)(bm * 16 + qt * 2 + (w >> 2)) * 8 + h) * 16);
#pragma unroll
  for (int i = 0; i < 2; i++)
#pragma unroll
    for (int j = 0; j < 4; j++) {
      long off = (cb0 + ((w & 3) * 2 + i) * 2 + (j >> 1)) * 512 +
                 (((((j & 1) << 1) | (m16 >> 3)) * 16 + quad * 4) * 8) + (m16 & 7);
#pragma unroll
      for (int r = 0; r < 4; r++)
        ctxf[off + r * 8] = f2bf(cacc[i][j][r] * linv[i][r]);
    }
}

extern "C" void kernel_launch(void* const* d_in, const int* in_sizes, int n_in,
                              void* d_out, int out_size, void* d_ws, size_t ws_size,
                              hipStream_t stream) {
  (void)in_sizes; (void)n_in; (void)out_size; (void)ws_size;
  const float* x = (const float*)d_in[0];
  const float* Wq = (const float*)d_in[1];
  const float* bq = (const float*)d_in[2];
  const float* Wkv = (const float*)d_in[3];
  const float* bkv = (const float*)d_in[4];
  const float* Wo = (const float*)d_in[5];
  const float* bo = (const float*)d_in[6];

  char* ws = (char*)d_ws;
  unsigned short* xf     = (unsigned short*)(ws);             // 16 MiB (reused as ctxf)
  unsigned short* Wqf    = (unsigned short*)(ws + 16777216);  // 512 KiB
  unsigned short* Wkvf   = (unsigned short*)(ws + 17301504);  // 512 KiB
  unsigned short* Wof    = (unsigned short*)(ws + 17825792);  // 512 KiB
  unsigned short* Qn_bf  = (unsigned short*)(ws + 18350080);  // 16 MiB
  unsigned short* Kf     = (unsigned short*)(ws + 35127296);  // 16 MiB
  unsigned short* Vf     = (unsigned short*)(ws + 51904512);  // 16 MiB
  unsigned short* ctxf   = xf;  // x dead after gemm_qkv

  cvt_all<<<8960, 256, 0, stream>>>(x, Wq, Wkv, Wo, xf, Wqf, Wkvf, Wof);

  gemm_qkv<<<dim3(128, 8), 256, 0, stream>>>(xf, Wqf, Wkvf, bq, bkv, Qn_bf, Kf, Vf);

  attn_cos<<<512, 512, 0, stream>>>(Qn_bf, Kf, Vf, ctxf);

  gemm_o<<<dim3(128, 4), 256, 0, stream>>>(ctxf, Wof, bo, (float*)d_out);
}

// Round 4
// 219.694 us; speedup vs baseline: 1.3568x; 1.0385x over previous
//
#include <hip/hip_runtime.h>

typedef __attribute__((ext_vector_type(8))) short bf16x8;
typedef __attribute__((ext_vector_type(8))) _Float16 f16x8;
typedef __attribute__((ext_vector_type(2))) _Float16 f16x2;
typedef __attribute__((ext_vector_type(4))) float f32x4;

__device__ __forceinline__ unsigned short f2bf(float f) {
  union { float f; unsigned int i; } v;
  v.f = f;
  unsigned int r = v.i + 0x7FFFu + ((v.i >> 16) & 1u);  // RNE
  return (unsigned short)(r >> 16);
}

__device__ __forceinline__ f16x2 cvt_pk(float a, float b) {
  return __builtin_bit_cast(f16x2, __builtin_amdgcn_cvt_pkrtz(a, b));
}

// async global->LDS, 16B/lane. LDS dst = wave-uniform base + lane*16.
// Global src MUST be base + lane*16 (contiguous 1KB) for full coalescing —
// all layouts below are fragment-major to guarantee this.
__device__ __forceinline__ void gl_lds16(const unsigned short* g, unsigned short* l) {
  __builtin_amdgcn_global_load_lds(
      (const __attribute__((address_space(1))) unsigned int*)g,
      (__attribute__((address_space(3))) unsigned int*)l, 16, 0, 0);
}

// e^x on [-1,1], Chebyshev-truncated degree 5 (abs err ~5e-5), packed f16.
__device__ __forceinline__ f16x2 exp_poly(f16x2 x) {
  const f16x2 a5 = {(_Float16)0.00868682f, (_Float16)0.00868682f};
  const f16x2 a4 = {(_Float16)0.04379392f, (_Float16)0.04379392f};
  const f16x2 a3 = {(_Float16)0.16648887f, (_Float16)0.16648887f};
  const f16x2 a2 = {(_Float16)0.49919676f, (_Float16)0.49919676f};
  const f16x2 a1 = {(_Float16)1.00002229f, (_Float16)1.00002229f};
  const f16x2 a0 = {(_Float16)1.00004478f, (_Float16)1.00004478f};
#if __has_builtin(__builtin_elementwise_fma)
  f16x2 r = a5;
  r = __builtin_elementwise_fma(r, x, a4);
  r = __builtin_elementwise_fma(r, x, a3);
  r = __builtin_elementwise_fma(r, x, a2);
  r = __builtin_elementwise_fma(r, x, a1);
  r = __builtin_elementwise_fma(r, x, a0);
#else
  f16x2 r = a5;
  r = r * x + a4;
  r = r * x + a3;
  r = r * x + a2;
  r = r * x + a1;
  r = r * x + a0;
#endif
  return r;
}

// ---------------- fp32 -> bf16 convert to FRAGMENT-MAJOR layout ----------------
// Layout: [rtile(=row>>7)][kb(=c>>6)][slot(=((row>>4)&7)*2+((c>>5)&1))]
//         [lane(=((c>>3)&3)*16+(row&15))][e(=c&7)]   (shorts)
__global__ __launch_bounds__(256) void cvt_all(
    const float* __restrict__ x, const float* __restrict__ wq,
    const float* __restrict__ wkv, const float* __restrict__ wo,
    unsigned short* __restrict__ xf, unsigned short* __restrict__ wqf,
    unsigned short* __restrict__ wkvf, unsigned short* __restrict__ wof) {
  int b = blockIdx.x;
  const float* in;
  unsigned short* out;
  int i;
  if (b < 8192) { in = x; out = xf; i = b * 256 + threadIdx.x; }
  else if (b < 8448) { in = wq; out = wqf; i = (b - 8192) * 256 + threadIdx.x; }
  else if (b < 8704) { in = wkv; out = wkvf; i = (b - 8448) * 256 + threadIdx.x; }
  else { in = wo; out = wof; i = (b - 8704) * 256 + threadIdx.x; }
  float4 v = ((const float4*)in)[i];
  int f = i << 2;
  int row = f >> 9, c = f & 511;
  long off = ((((long)(row >> 7) * 8 + (c >> 6)) * 16 + ((row >> 4) & 7) * 2 +
               ((c >> 5) & 1)) * 64 + ((c >> 3) & 3) * 16 + (row & 15)) * 8 + (c & 7);
  ushort4 o;
  o.x = f2bf(v.x);
  o.y = f2bf(v.y);
  o.z = f2bf(v.z);
  o.w = f2bf(v.w);
  *(ushort4*)(out + off) = o;
}

// ---------------- fused Q + KV projection GEMM (fragment-major in) ----------------
// grid (128, 8): y<4 -> Q half (Qn bf16 normalized, row-major),
// y>=4 -> KV half (Kf bf16 normalized fragment-major + Vf f16 V^T fragment-major).
// Kf/Vf layout: [(g*32+kt)*8 + slot][lane][8] shorts, 1KB per slot.
__global__ __launch_bounds__(256) void gemm_qkv(
    const unsigned short* __restrict__ xf, const unsigned short* __restrict__ Wqf,
    const unsigned short* __restrict__ Wkvf, const float* __restrict__ bq,
    const float* __restrict__ bkv, unsigned short* __restrict__ Qn,
    unsigned short* __restrict__ Kf, unsigned short* __restrict__ Vf) {
  __shared__ __attribute__((aligned(16))) unsigned short lA[16 * 512];
  __shared__ __attribute__((aligned(16))) unsigned short lB[16 * 512];
  const int isKV = (int)(blockIdx.y >> 2);
  const unsigned short* Btf = isKV ? Wkvf : Wqf;
  const float* bias = isKV ? bkv : bq;
  const int tid = threadIdx.x;
  const int lane = tid & 63;
  const int quad = lane >> 4, m16 = lane & 15;
  const int w = tid >> 6;
  const int wm = w >> 1, wn = w & 1;
  const long mb = (long)blockIdx.x * 128;
  const int nt = (int)(blockIdx.y & 3);
  const long nb = (long)nt * 128;
  f32x4 acc[4][4];
#pragma unroll
  for (int i = 0; i < 4; i++)
#pragma unroll
    for (int j = 0; j < 4; j++) acc[i][j] = (f32x4){0.f, 0.f, 0.f, 0.f};

  for (int kb = 0; kb < 8; kb++) {
    __syncthreads();
    {
      const unsigned short* gA =
          xf + (((long)blockIdx.x * 8 + kb) * 16 + 4 * w) * 512 + lane * 8;
      gl_lds16(gA, &lA[(4 * w + 0) * 512]);
      gl_lds16(gA + 512, &lA[(4 * w + 1) * 512]);
      gl_lds16(gA + 1024, &lA[(4 * w + 2) * 512]);
      gl_lds16(gA + 1536, &lA[(4 * w + 3) * 512]);
      const unsigned short* gB =
          Btf + (((long)nt * 8 + kb) * 16 + 4 * w) * 512 + lane * 8;
      gl_lds16(gB, &lB[(4 * w + 0) * 512]);
      gl_lds16(gB + 512, &lB[(4 * w + 1) * 512]);
      gl_lds16(gB + 1024, &lB[(4 * w + 2) * 512]);
      gl_lds16(gB + 1536, &lB[(4 * w + 3) * 512]);
    }
    __syncthreads();
#pragma unroll
    for (int ks = 0; ks < 2; ks++) {
      bf16x8 af[4], bfr[4];
#pragma unroll
      for (int i = 0; i < 4; i++)
        af[i] = *(const bf16x8*)&lA[(((wm * 4 + i) << 1) | ks) * 512 + lane * 8];
#pragma unroll
      for (int j = 0; j < 4; j++)
        bfr[j] = *(const bf16x8*)&lB[(((wn * 4 + j) << 1) | ks) * 512 + lane * 8];
#pragma unroll
      for (int i = 0; i < 4; i++)
#pragma unroll
        for (int j = 0; j < 4; j++)
          acc[i][j] =
              __builtin_amdgcn_mfma_f32_16x16x32_bf16(af[i], bfr[j], acc[i][j], 0, 0, 0);
    }
  }
  const int h = (int)(nb >> 6) + wn;  // head is constant per wave-column
#pragma unroll
  for (int i = 0; i < 4; i++) {
    long row0 = mb + wm * 64 + i * 16 + quad * 4;
    float bb[4], val[4][4], inv[4];
#pragma unroll
    for (int j = 0; j < 4; j++) {
      bb[j] = bias[nb + wn * 64 + j * 16 + m16];
#pragma unroll
      for (int r = 0; r < 4; r++) val[j][r] = acc[i][j][r] + bb[j];
    }
#pragma unroll
    for (int r = 0; r < 4; r++) {
      float s = val[0][r] * val[0][r] + val[1][r] * val[1][r] +
                val[2][r] * val[2][r] + val[3][r] * val[3][r];
      s += __shfl_xor(s, 1);
      s += __shfl_xor(s, 2);
      s += __shfl_xor(s, 4);
      s += __shfl_xor(s, 8);
      inv[r] = 1.0f / fmaxf(sqrtf(s), 1e-12f);
    }
    if (!isKV) {
#pragma unroll
      for (int r = 0; r < 4; r++)
#pragma unroll
        for (int j = 0; j < 4; j++) {
          long col = nb + wn * 64 + j * 16 + m16;
          Qn[(row0 + r) * 512 + col] = f2bf(val[j][r] * inv[r]);
        }
    } else {
      const int bm = (int)(row0 >> 11);
      const int g = bm * 8 + h;
      const int kt = (int)((row0 & 2047) >> 6);
      const long tb = ((long)g * 32 + kt) * 8;
      // Kf: element (s,d): slot = i*2+(d>>5), lane = ((d>>3)&3)*16 + (s&15), e = d&7
      //     here d = j*16+m16 -> (d>>5)=j>>1, (d>>3)&3 = ((j&1)<<1)|(m16>>3)
#pragma unroll
      for (int j = 0; j < 4; j++) {
        long kb0 = (tb + i * 2 + (j >> 1)) * 512 +
                   (((((j & 1) << 1) | (m16 >> 3)) * 16 + quad * 4) * 8) + (m16 & 7);
#pragma unroll
        for (int r = 0; r < 4; r++) Kf[kb0 + r * 8] = f2bf(val[j][r] * inv[r]);
      }
      // Vf (V^T): element (d,k): slot = j*2+(i>>1),
      //   lane = (((i&1)<<1)|(quad>>1))*16 + m16, e = (quad&1)*4 + r (contiguous!)
#pragma unroll
      for (int j = 0; j < 4; j++) {
        long vo = (tb + j * 2 + (i >> 1)) * 512 +
                  ((((((i & 1) << 1) | (quad >> 1)) * 16 + m16)) * 8) + (quad & 1) * 4;
        f16x2 lo = cvt_pk(val[j][0], val[j][1]);
        f16x2 hi = cvt_pk(val[j][2], val[j][3]);
        uint2 pk = make_uint2(__builtin_bit_cast(unsigned int, lo),
                              __builtin_bit_cast(unsigned int, hi));
        *(uint2*)(Vf + vo) = pk;
      }
    }
  }
}

// ---------------- output projection GEMM (fragment-major in, f32 out) ----------------
__global__ __launch_bounds__(256) void gemm_o(
    const unsigned short* __restrict__ Af, const unsigned short* __restrict__ Btf,
    const float* __restrict__ bias, float* __restrict__ Cout) {
  __shared__ __attribute__((aligned(16))) unsigned short lA[16 * 512];
  __shared__ __attribute__((aligned(16))) unsigned short lB[16 * 512];
  const int tid = threadIdx.x;
  const int lane = tid & 63;
  const int quad = lane >> 4, m16 = lane & 15;
  const int w = tid >> 6;
  const int wm = w >> 1, wn = w & 1;
  const long mb = (long)blockIdx.x * 128;
  const int nt = (int)blockIdx.y;
  const long nb = (long)nt * 128;
  f32x4 acc[4][4];
#pragma unroll
  for (int i = 0; i < 4; i++)
#pragma unroll
    for (int j = 0; j < 4; j++) acc[i][j] = (f32x4){0.f, 0.f, 0.f, 0.f};

  for (int kb = 0; kb < 8; kb++) {
    __syncthreads();
    {
      const unsigned short* gA =
          Af + (((long)blockIdx.x * 8 + kb) * 16 + 4 * w) * 512 + lane * 8;
      gl_lds16(gA, &lA[(4 * w + 0) * 512]);
      gl_lds16(gA + 512, &lA[(4 * w + 1) * 512]);
      gl_lds16(gA + 1024, &lA[(4 * w + 2) * 512]);
      gl_lds16(gA + 1536, &lA[(4 * w + 3) * 512]);
      const unsigned short* gB =
          Btf + (((long)nt * 8 + kb) * 16 + 4 * w) * 512 + lane * 8;
      gl_lds16(gB, &lB[(4 * w + 0) * 512]);
      gl_lds16(gB + 512, &lB[(4 * w + 1) * 512]);
      gl_lds16(gB + 1024, &lB[(4 * w + 2) * 512]);
      gl_lds16(gB + 1536, &lB[(4 * w + 3) * 512]);
    }
    __syncthreads();
#pragma unroll
    for (int ks = 0; ks < 2; ks++) {
      bf16x8 af[4], bfr[4];
#pragma unroll
      for (int i = 0; i < 4; i++)
        af[i] = *(const bf16x8*)&lA[(((wm * 4 + i) << 1) | ks) * 512 + lane * 8];
#pragma unroll
      for (int j = 0; j < 4; j++)
        bfr[j] = *(const bf16x8*)&lB[(((wn * 4 + j) << 1) | ks) * 512 + lane * 8];
#pragma unroll
      for (int i = 0; i < 4; i++)
#pragma unroll
        for (int j = 0; j < 4; j++)
          acc[i][j] =
              __builtin_amdgcn_mfma_f32_16x16x32_bf16(af[i], bfr[j], acc[i][j], 0, 0, 0);
    }
  }
#pragma unroll
  for (int i = 0; i < 4; i++) {
    long row0 = mb + wm * 64 + i * 16 + quad * 4;
#pragma unroll
    for (int j = 0; j < 4; j++) {
      long col = nb + wn * 64 + j * 16 + m16;
      float bb = bias[col];
#pragma unroll
      for (int r = 0; r < 4; r++) Cout[(row0 + r) * 512 + col] = acc[i][j][r] + bb;
    }
  }
}

// ---------------- cosine attention (LDS-minimized, double-buffered) ----------------
// Round-3 PMC showed the LDS pipe saturated (~7100 cyc/CU-kt, matching 36
// b128 reads/wave-kt); this version hoists K/V fragment reads out of the
// i-loop (36 -> 20 b128 reads/wave-kt) and double-buffers the K/V stage so
// there is ONE barrier per kt (stage for kt+1 issued right after the
// consuming barrier; end-of-kt __syncthreads' implicit vmcnt(0) lands after
// the full compute phase -> stage latency hidden).
// Grid decode unchanged from r3 (keeps FETCH at ~25 MB: 8 distinct groups
// per XCD under both round-robin and chunked XCD assignment).
__global__ __launch_bounds__(512, 4) void attn_cos(
    const unsigned short* __restrict__ Qn, const unsigned short* __restrict__ Kf,
    const unsigned short* __restrict__ Vf, unsigned short* __restrict__ ctxf) {
  __shared__ __attribute__((aligned(16))) unsigned short lK[2][8 * 512];   // 16 KB
  __shared__ __attribute__((aligned(16))) unsigned short lVt[2][8 * 512];  // 16 KB
  __shared__ __attribute__((aligned(16))) unsigned short lP[256 * 64];     // 32 KB
  const int id = (int)blockIdx.x;
  const int g = ((id >> 6) << 3) | (id & 7);  // 0..63
  const int qt = (id >> 3) & 7;               // 0..7 (256-row tiles)
  const int bm = g >> 3, h = g & 7;
  const int tid = threadIdx.x;
  const int lane = tid & 63;
  const int quad = lane >> 4, m16 = lane & 15;
  const int w = tid >> 6;  // 0..7
  const long qrow0 = (long)bm * 2048 + qt * 256 + w * 32;
  const int colbase = h * 64;
  const int swz = (m16 & 7) << 3;            // lP XOR swizzle key
  unsigned short* myP = lP + (w * 32) * 64;  // wave-private 4KB (32 rows)

  // Q B-fragments (fixed for all k-tiles; one-time strided load, row-major Qn)
  bf16x8 qf[2][2];
#pragma unroll
  for (int i = 0; i < 2; i++)
#pragma unroll
    for (int ks = 0; ks < 2; ks++)
      qf[i][ks] = *(const bf16x8*)(Qn + (qrow0 + i * 16 + m16) * 512 + colbase +
                                   ks * 32 + quad * 8);

  f32x4 cacc[2][4];
#pragma unroll
  for (int i = 0; i < 2; i++)
#pragma unroll
    for (int j = 0; j < 4; j++) cacc[i][j] = (f32x4){0.f, 0.f, 0.f, 0.f};
  f32x4 cacc_l[2];  // li via PV-ones MFMA: every column of D = row-sum of P
  cacc_l[0] = (f32x4){0.f, 0.f, 0.f, 0.f};
  cacc_l[1] = (f32x4){0.f, 0.f, 0.f, 0.f};
  const f16x8 onesv = {(_Float16)1.0f, (_Float16)1.0f, (_Float16)1.0f, (_Float16)1.0f,
                       (_Float16)1.0f, (_Float16)1.0f, (_Float16)1.0f, (_Float16)1.0f};

  // prologue: stage kt=0 into buffer 0 (wave w fills slot w of K and V)
  {
    const long tb0 = (long)g * 32 * 8;
    gl_lds16(Kf + (tb0 + w) * 512 + lane * 8, &lK[0][w * 512]);
    gl_lds16(Vf + (tb0 + w) * 512 + lane * 8, &lVt[0][w * 512]);
  }
  __syncthreads();  // implicit vmcnt(0): buffer 0 ready

  int cur = 0;
  for (int kt = 0; kt < 32; ++kt) {
    // issue stage of kt+1 into the other buffer (async; completes during compute)
    {
      const int ktn = (kt + 1) & 31;  // wraps on last iter: harmless in-bounds fetch
      const long tbn = ((long)g * 32 + ktn) * 8;
      gl_lds16(Kf + (tbn + w) * 512 + lane * 8, &lK[cur ^ 1][w * 512]);
      gl_lds16(Vf + (tbn + w) * 512 + lane * 8, &lVt[cur ^ 1][w * 512]);
    }

    // ---- QK^T: ks-outer so each K fragment is read from LDS ONCE per kt ----
    f32x4 sacc[2][4];
#pragma unroll
    for (int i = 0; i < 2; i++)
#pragma unroll
      for (int j = 0; j < 4; j++) sacc[i][j] = (f32x4){0.f, 0.f, 0.f, 0.f};
#pragma unroll
    for (int ks = 0; ks < 2; ++ks) {
      bf16x8 kfr[4];
#pragma unroll
      for (int j = 0; j < 4; j++)
        kfr[j] = *(const bf16x8*)&lK[cur][((j << 1) | ks) * 512 + lane * 8];
#pragma unroll
      for (int j = 0; j < 4; j++)
#pragma unroll
        for (int i = 0; i < 2; i++)
          sacc[i][j] = __builtin_amdgcn_mfma_f32_16x16x32_bf16(kfr[j], qf[i][ks],
                                                               sacc[i][j], 0, 0, 0);
    }

    // ---- packed-f16 exp + swizzled P write (wave-private rows) ----
#pragma unroll
    for (int i = 0; i < 2; i++)
#pragma unroll
      for (int j = 0; j < 4; j++) {
        f16x2 x01 = cvt_pk(sacc[i][j][0], sacc[i][j][1]);
        f16x2 x23 = cvt_pk(sacc[i][j][2], sacc[i][j][3]);
        f16x2 e01 = exp_poly(x01);
        f16x2 e23 = exp_poly(x23);
        uint2 pk2 = make_uint2(__builtin_bit_cast(unsigned int, e01),
                               __builtin_bit_cast(unsigned int, e23));
        *(uint2*)&myP[(i * 16 + m16) * 64 + ((j * 16 + quad * 4) ^ swz)] = pk2;
      }

    // ---- PV: ks-outer so each V fragment is read from LDS ONCE per kt ----
#pragma unroll
    for (int ks = 0; ks < 2; ++ks) {
      f16x8 vfr[4];
#pragma unroll
      for (int j = 0; j < 4; j++)
        vfr[j] = *(const f16x8*)&lVt[cur][((j << 1) | ks) * 512 + lane * 8];
      f16x8 pfr[2];
#pragma unroll
      for (int i = 0; i < 2; i++)
        pfr[i] = *(const f16x8*)&myP[(i * 16 + m16) * 64 +
                                     ((ks * 32 + quad * 8) ^ swz)];
#pragma unroll
      for (int i = 0; i < 2; i++) {
#pragma unroll
        for (int j = 0; j < 4; j++)
          cacc[i][j] = __builtin_amdgcn_mfma_f32_16x16x32_f16(pfr[i], vfr[j],
                                                              cacc[i][j], 0, 0, 0);
        cacc_l[i] =
            __builtin_amdgcn_mfma_f32_16x16x32_f16(pfr[i], onesv, cacc_l[i], 0, 0, 0);
      }
    }

    // ONE barrier per kt: orders this iter's LDS reads before next iter's
    // stage-writes, and its implicit vmcnt(0) guarantees the async stage of
    // kt+1 (issued ~2000 cyc ago) has landed.
    __syncthreads();
    cur ^= 1;
  }

  // li rows of cacc_l match cacc rows -> no shuffles needed
  float linv[2][4];
#pragma unroll
  for (int i = 0; i < 2; i++)
#pragma unroll
    for (int r = 0; r < 4; r++) linv[i][r] = 1.0f / cacc_l[i][r];
  // epilogue: write ctx FRAGMENT-MAJOR for gemm_o:
  // rtile = bm*16 + qt*2 + (w>>2), kb = h, slot = ((w&3)*2+i)*2 + (j>>1),
  // lane = (((j&1)<<1)|(m16>>3))*16 + quad*4 + r, e = m16&7
  const long cb0 = (((long)(bm * 16 + qt * 2 + (w >> 2)) * 8 + h) * 16);
#pragma unroll
  for (int i = 0; i < 2; i++)
#pragma unroll
    for (int j = 0; j < 4; j++) {
      long off = (cb0 + ((w & 3) * 2 + i) * 2 + (j >> 1)) * 512 +
                 (((((j & 1) << 1) | (m16 >> 3)) * 16 + quad * 4) * 8) + (m16 & 7);
#pragma unroll
      for (int r = 0; r < 4; r++)
        ctxf[off + r * 8] = f2bf(cacc[i][j][r] * linv[i][r]);
    }
}

extern "C" void kernel_launch(void* const* d_in, const int* in_sizes, int n_in,
                              void* d_out, int out_size, void* d_ws, size_t ws_size,
                              hipStream_t stream) {
  (void)in_sizes; (void)n_in; (void)out_size; (void)ws_size;
  const float* x = (const float*)d_in[0];
  const float* Wq = (const float*)d_in[1];
  const float* bq = (const float*)d_in[2];
  const float* Wkv = (const float*)d_in[3];
  const float* bkv = (const float*)d_in[4];
  const float* Wo = (const float*)d_in[5];
  const float* bo = (const float*)d_in[6];

  char* ws = (char*)d_ws;
  unsigned short* xf     = (unsigned short*)(ws);             // 16 MiB (reused as ctxf)
  unsigned short* Wqf    = (unsigned short*)(ws + 16777216);  // 512 KiB
  unsigned short* Wkvf   = (unsigned short*)(ws + 17301504);  // 512 KiB
  unsigned short* Wof    = (unsigned short*)(ws + 17825792);  // 512 KiB
  unsigned short* Qn_bf  = (unsigned short*)(ws + 18350080);  // 16 MiB
  unsigned short* Kf     = (unsigned short*)(ws + 35127296);  // 16 MiB
  unsigned short* Vf     = (unsigned short*)(ws + 51904512);  // 16 MiB
  unsigned short* ctxf   = xf;  // x dead after gemm_qkv

  cvt_all<<<8960, 256, 0, stream>>>(x, Wq, Wkv, Wo, xf, Wqf, Wkvf, Wof);

  gemm_qkv<<<dim3(128, 8), 256, 0, stream>>>(xf, Wqf, Wkvf, bq, bkv, Qn_bf, Kf, Vf);

  attn_cos<<<512, 512, 0, stream>>>(Qn_bf, Kf, Vf, ctxf);

  gemm_o<<<dim3(128, 4), 256, 0, stream>>>(ctxf, Wof, bo, (float*)d_out);
}